// Round 8
// baseline (679.607 us; speedup 1.0000x reference)
//
#include <hip/hip_runtime.h>
#include <stdint.h>

// ---------------------------------------------------------------------------
// Axis_Horizontal_Attention, MI355X (gfx950).  B=16, C=256, H=W=128, fp32.
// Round 8: spart2 rewrite -- A(q) fragments direct-from-global (coalesced,
// no LDS round-trip), k staging split into load(regs)/write(LDS) around the
// MFMA block, double-buffered, one barrier per K-step.  Rest = round 7.
// ---------------------------------------------------------------------------

typedef _Float16 f16;
typedef __attribute__((ext_vector_type(8))) _Float16 f16x8;
typedef __attribute__((ext_vector_type(4))) float f32x4;
typedef __attribute__((ext_vector_type(4))) unsigned u32x4;

#define DEV static __device__ __forceinline__

constexpr int  HW   = 16384;     // H*W
constexpr long PB   = 4194304;   // C*H*W per batch
constexpr long HALF = 2097152;   // HW*128

// ws layout (bytes): W images only (~0.9 MB)
constexpr long WH_OFF  = 0;                      // [3][8][256][64B]
constexpr long WL_OFF  = 393216;
constexpr long WU_OFF  = 786432;                 // [8][256][64B], gamma-folded
constexpr long WS_NEED = 1048576;

DEV unsigned pk2(float a, float b) {
  auto h = __builtin_amdgcn_cvt_pkrtz(a, b);
  return __builtin_bit_cast(unsigned, h);
}
DEV void split_pk2(float a, float b, unsigned& hu, unsigned& lu) {
  auto h = __builtin_amdgcn_cvt_pkrtz(a, b);
  auto l = __builtin_amdgcn_cvt_pkrtz(a - (float)h[0], b - (float)h[1]);
  hu = __builtin_bit_cast(unsigned, h);
  lu = __builtin_bit_cast(unsigned, l);
}
DEV f32x4 mfma16(f16x8 a, f16x8 b, f32x4 c) {
  return __builtin_amdgcn_mfma_f32_16x16x32_f16(a, b, c, 0, 0, 0);
}
// 64B-row image layout, granule swizzle; works for LDS and global pointers.
DEV f16x8 ld64(const char* base, int row, int g) {
  return *(const f16x8*)(base + row * 64 + 16 * (g ^ ((row >> 1) & 3)));
}

DEV void gload16(const void* g, void* l) {
  __builtin_amdgcn_global_load_lds(
      (const __attribute__((address_space(1))) uint32_t*)(g),
      (__attribute__((address_space(3))) uint32_t*)(l), 16, 0, 0);
}

// generic padded-row LDS frag helpers
DEV int swz(int row, int kbyte) {
  return (kbyte & ~63) | ((kbyte & 63) ^ (((row >> 3) & 3) << 4));
}
DEV f16x8 ldfrag(const f16* arr, int strideB, int row, int kbyte) {
  return *(const f16x8*)((const char*)arr + row * strideB + swz(row, kbyte));
}

// ---------------------------------------------------------------------------
// prepass W: split Wq/Wk/Wv (hi/lo) and gamma*Wup (hi) into swizzled
// image layout.  grid (8 kc, 4 m), block 256 (thread = o row).
// ---------------------------------------------------------------------------
__global__ __launch_bounds__(256) void prep_w(
    const float* __restrict__ Wq, const float* __restrict__ Wk,
    const float* __restrict__ Wv, const float* __restrict__ Wu,
    const float* __restrict__ gin, char* __restrict__ ws) {
  const int kc = blockIdx.x, m = blockIdx.y, o = threadIdx.x;
  const float* src = (m == 0) ? Wq : (m == 1) ? Wk : (m == 2) ? Wv : Wu;
  const float sc = (m == 3) ? gin[0] : 1.0f;
  float v[32];
#pragma unroll
  for (int j = 0; j < 32; ++j) v[j] = src[o * 256 + kc * 32 + j] * sc;
  char* dh = (m < 3) ? (ws + WH_OFF + ((long)(m * 8 + kc) * 256 + o) * 64)
                     : (ws + WU_OFF + ((long)kc * 256 + o) * 64);
  char* dl = ws + WL_OFF + ((long)(m * 8 + kc) * 256 + o) * 64;
  const int sw = (o >> 1) & 3;
#pragma unroll
  for (int gq = 0; gq < 4; ++gq) {
    unsigned h[4], l[4];
#pragma unroll
    for (int p = 0; p < 4; ++p)
      split_pk2(v[8 * gq + 2 * p], v[8 * gq + 2 * p + 1], h[p], l[p]);
    const int off = 16 * (gq ^ sw);
    *(uint4*)(dh + off) = make_uint4(h[0], h[1], h[2], h[3]);
    if (m < 3) *(uint4*)(dl + off) = make_uint4(l[0], l[1], l[2], l[3]);
  }
}

// ---------------------------------------------------------------------------
// qkv_fused3: relu(Wq@X), relu(Wk@X), relu(Wv@X) for one (b, 64-hw) slice.
// (unchanged from round 7)
// ---------------------------------------------------------------------------
__global__ __launch_bounds__(256, 2) void qkv_fused3(
    const float* __restrict__ x,
    const char* __restrict__ wqh, const char* __restrict__ wql,
    const char* __restrict__ wkh, const char* __restrict__ wkl,
    const char* __restrict__ wvh,
    float* __restrict__ qseg, float* __restrict__ kseg,
    float* __restrict__ vseg) {
  __shared__ char lds[65536];
  char* Xh = lds;              // [8 kc][64 hw][64B]
  char* Xl = lds + 32768;
  float* R = (float*)(lds + 32768);  // repack buffer, reuses Xl after k MFMA
  const int t = threadIdx.x, lane = t & 63, w = t >> 6;
  const int l15 = lane & 15, g = lane >> 4;
  const int b = blockIdx.y, hw0 = blockIdx.x * 64;
  const float* xb = x + (long)b * PB + hw0;

  // ---- stage: x slice [256 c][64 hw] -> transpose + hi/lo split into LDS
  {
    const int hw = t & 63, cq = t >> 6;
    const int sw = (hw >> 1) & 3;
#pragma unroll
    for (int j8 = 0; j8 < 8; ++j8) {
      const int c0 = cq * 64 + j8 * 8;
      float v[8];
#pragma unroll
      for (int i = 0; i < 8; ++i) v[i] = xb[(long)(c0 + i) * HW + hw];
      unsigned h[4], l[4];
#pragma unroll
      for (int p = 0; p < 4; ++p)
        split_pk2(v[2 * p], v[2 * p + 1], h[p], l[p]);
      const int kc = c0 >> 5, gi = (c0 >> 3) & 3;
      const int off = kc * 4096 + hw * 64 + 16 * (gi ^ sw);
      *(uint4*)(Xh + off) = make_uint4(h[0], h[1], h[2], h[3]);
      *(uint4*)(Xl + off) = make_uint4(l[0], l[1], l[2], l[3]);
    }
  }
  __syncthreads();

  auto repack_store = [&](f32x4 (&ac)[4][4], float* ob) {
#pragma unroll
    for (int half = 0; half < 2; ++half) {
#pragma unroll
      for (int mf2 = 0; mf2 < 2; ++mf2) {
        const int mf = 2 * half + mf2;
#pragma unroll
        for (int nf = 0; nf < 4; ++nf)
#pragma unroll
          for (int r = 0; r < 4; ++r) {
            const int hwloc = 16 * mf2 + 4 * g + r;
            const int o = w * 64 + 16 * nf + l15;
            const int col = (o >> 1) ^ (((hwloc >> 2) & 3) << 3);
            float v = ac[mf][nf][r];
            R[(o & 1) * 4096 + hwloc * 128 + col] = v > 0.f ? v : 0.f;
          }
      }
      __syncthreads();
#pragma unroll
      for (int it = 0; it < 8; ++it) {
        const int f = t + 256 * it;  // [2 parity][32 hwloc][32 q4]
        const int parity = f >> 10, hwloc = (f >> 5) & 31, q4 = f & 31;
        const int col = (4 * q4) ^ (((hwloc >> 2) & 3) << 3);
        const float4 v4 = *(const float4*)(R + parity * 4096 + hwloc * 128 + col);
        *(float4*)(ob + (long)parity * HALF +
                   (long)(hw0 + 32 * half + hwloc) * 128 + 4 * q4) = v4;
      }
      __syncthreads();
    }
  };

  // ---- q pass
  {
    f32x4 acc[4][4] = {};
    for (int kc = 0; kc < 8; ++kc) {
      const char* XH = Xh + kc * 4096;
      const char* XL = Xl + kc * 4096;
      const char* WH = wqh + (long)kc * 16384;
      const char* WL = wql + (long)kc * 16384;
      f16x8 bh[4], bl[4];
#pragma unroll
      for (int nf = 0; nf < 4; ++nf) {
        bh[nf] = ld64(XH, 16 * nf + l15, g);
        bl[nf] = ld64(XL, 16 * nf + l15, g);
      }
#pragma unroll
      for (int mf = 0; mf < 4; ++mf) {
        const int orow = w * 64 + 16 * mf + l15;
        f16x8 ah = ld64(WH, orow, g);
        f16x8 al = ld64(WL, orow, g);
#pragma unroll
        for (int nf = 0; nf < 4; ++nf) {
          acc[mf][nf] = mfma16(ah, bh[nf], acc[mf][nf]);
          acc[mf][nf] = mfma16(ah, bl[nf], acc[mf][nf]);
          acc[mf][nf] = mfma16(al, bh[nf], acc[mf][nf]);
        }
      }
    }
    float* ob = qseg + (long)b * PB;
#pragma unroll
    for (int mf = 0; mf < 4; ++mf)
#pragma unroll
      for (int nf = 0; nf < 4; ++nf)
#pragma unroll
        for (int r = 0; r < 4; ++r) {
          float v = acc[mf][nf][r];
          v = v > 0.f ? v : 0.f;
          const int o = w * 64 + 16 * mf + 4 * g + r;
          const int hw = hw0 + 16 * nf + l15;
          ob[(long)o * HW + hw] = v;
        }
  }

  // ---- k pass
  {
    f32x4 acc[4][4] = {};
    for (int kc = 0; kc < 8; ++kc) {
      const char* XH = Xh + kc * 4096;
      const char* XL = Xl + kc * 4096;
      const char* WH = wkh + (long)kc * 16384;
      const char* WL = wkl + (long)kc * 16384;
      f16x8 bh[4], bl[4];
#pragma unroll
      for (int nf = 0; nf < 4; ++nf) {
        const int orow = w * 64 + 16 * nf + l15;
        bh[nf] = ld64(WH, orow, g);
        bl[nf] = ld64(WL, orow, g);
      }
#pragma unroll
      for (int mf = 0; mf < 4; ++mf) {
        f16x8 ah = ld64(XH, 16 * mf + l15, g);
        f16x8 al = ld64(XL, 16 * mf + l15, g);
#pragma unroll
        for (int nf = 0; nf < 4; ++nf) {
          acc[mf][nf] = mfma16(ah, bh[nf], acc[mf][nf]);
          acc[mf][nf] = mfma16(ah, bl[nf], acc[mf][nf]);
          acc[mf][nf] = mfma16(al, bh[nf], acc[mf][nf]);
        }
      }
    }
    __syncthreads();  // all Xl reads complete before R overwrites it
    repack_store(acc, kseg + (long)b * PB);
  }

  // ---- v pass: hi-only
  {
    f32x4 acc[4][4] = {};
    for (int kc = 0; kc < 8; ++kc) {
      const char* XH = Xh + kc * 4096;
      const char* WH = wvh + (long)kc * 16384;
      f16x8 bh[4];
#pragma unroll
      for (int nf = 0; nf < 4; ++nf)
        bh[nf] = ld64(WH, w * 64 + 16 * nf + l15, g);
#pragma unroll
      for (int mf = 0; mf < 4; ++mf) {
        f16x8 ah = ld64(XH, 16 * mf + l15, g);
#pragma unroll
        for (int nf = 0; nf < 4; ++nf)
          acc[mf][nf] = mfma16(ah, bh[nf], acc[mf][nf]);
      }
    }
    repack_store(acc, vseg + (long)b * PB);
  }
}

// ---------------------------------------------------------------------------
// spart2: S partials, K-split 32 chunks.  A(q) fragments direct-from-global
// (coalesced 128B/row), k staged load(regs)->MFMA->write(LDS), dbuf,
// one barrier per K-step.  grid (32 ch, 16 b), block 256.
// ---------------------------------------------------------------------------
__global__ __launch_bounds__(256, 2) void spart2(
    const float* __restrict__ qseg, const float* __restrict__ kseg,
    float* __restrict__ part) {
  constexpr int SB = 80;
  __shared__ f16 Bh[2][128 * 40], Bl[2][128 * 40];
  const int t = threadIdx.x, lane = t & 63, w = t >> 6;
  const int l15 = lane & 15, g = lane >> 4;
  const int ch = blockIdx.x, b = blockIdx.y;
  const float* qb = qseg + (long)b * PB + ch * 1024;
  const float* kb = kseg + (long)b * PB + (long)ch * 1024 * 128;
  const int kc_col = t & 127, kc_rh = t >> 7;  // staging coords
  const int ar0 = (w & 1) * 64, br0 = (w >> 1) * 64;

  float kv[16];
  auto loadB = [&](int kc) {
#pragma unroll
    for (int r = 0; r < 16; ++r)
      kv[r] = kb[(long)(kc + 16 * kc_rh + r) * 128 + kc_col];
  };
  auto writeB = [&](int buf) {
#pragma unroll
    for (int u = 0; u < 4; ++u) {
      unsigned h0, l0, h1, l1;
      split_pk2(kv[4 * u], kv[4 * u + 1], h0, l0);
      split_pk2(kv[4 * u + 2], kv[4 * u + 3], h1, l1);
      const int kbo = swz(kc_col, 32 * kc_rh + 8 * u);
      *(uint2*)((char*)Bh[buf] + kc_col * SB + kbo) = make_uint2(h0, h1);
      *(uint2*)((char*)Bl[buf] + kc_col * SB + kbo) = make_uint2(l0, l1);
    }
  };

  f32x4 acc[4][4] = {};
  loadB(0);
  writeB(0);
  __syncthreads();

  for (int s = 0; s < 32; ++s) {
    const int kc = s * 32;
    // A (q) loads first -> oldest in VM queue; waiting on them leaves the
    // k loads (issued next) in flight.
    f32x4 av[4][2];
#pragma unroll
    for (int mf = 0; mf < 4; ++mf) {
      const float* src = qb + (long)(ar0 + 16 * mf + l15) * 32768 + kc + 8 * g;
      av[mf][0] = *(const f32x4*)src;
      av[mf][1] = *(const f32x4*)(src + 4);
    }
    if (s < 31) loadB(kc + 32);  // next-step k loads, hidden under MFMAs

    // A split -> frags
    f16x8 afh[4], afl[4];
#pragma unroll
    for (int mf = 0; mf < 4; ++mf) {
      unsigned h0, l0, h1, l1, h2, l2, h3, l3;
      split_pk2(av[mf][0][0], av[mf][0][1], h0, l0);
      split_pk2(av[mf][0][2], av[mf][0][3], h1, l1);
      split_pk2(av[mf][1][0], av[mf][1][1], h2, l2);
      split_pk2(av[mf][1][2], av[mf][1][3], h3, l3);
      u32x4 uh = {h0, h1, h2, h3};
      u32x4 ul = {l0, l1, l2, l3};
      afh[mf] = __builtin_bit_cast(f16x8, uh);
      afl[mf] = __builtin_bit_cast(f16x8, ul);
    }
    // B frags from LDS (current buffer)
    const f16* BH = Bh[s & 1];
    const f16* BL = Bl[s & 1];
    f16x8 bfh[4], bfl[4];
#pragma unroll
    for (int f = 0; f < 4; ++f) {
      bfh[f] = ldfrag(BH, SB, br0 + 16 * f + l15, 16 * g);
      bfl[f] = ldfrag(BL, SB, br0 + 16 * f + l15, 16 * g);
    }
#pragma unroll
    for (int mf = 0; mf < 4; ++mf)
#pragma unroll
      for (int nf = 0; nf < 4; ++nf) {
        acc[mf][nf] = mfma16(afh[mf], bfh[nf], acc[mf][nf]);
        acc[mf][nf] = mfma16(afh[mf], bfl[nf], acc[mf][nf]);
        acc[mf][nf] = mfma16(afl[mf], bfh[nf], acc[mf][nf]);
      }

    if (s < 31) writeB((s + 1) & 1);  // split+LDS-write after MFMAs
    __syncthreads();
  }

  float* pp = part + (long)(b * 32 + ch) * 16384;
#pragma unroll
  for (int mf = 0; mf < 4; ++mf)
#pragma unroll
    for (int nf = 0; nf < 4; ++nf)
#pragma unroll
      for (int r = 0; r < 4; ++r) {
        int i = ar0 + 16 * mf + 4 * g + r;
        int i2 = br0 + 16 * nf + l15;
        pp[i * 128 + i2] = acc[mf][nf][r];
      }
}

// ---------------------------------------------------------------------------
// reduce_s: sum 32 partial S chunks -> S (into attn segment) + gamma.
// ---------------------------------------------------------------------------
__global__ __launch_bounds__(128) void reduce_s(
    const float* __restrict__ part, float* __restrict__ att,
    float* __restrict__ gout, const float* __restrict__ gin) {
  const int i = blockIdx.x, b = blockIdx.y, t = threadIdx.x;
  if (b == 0 && i == 0 && t == 0) gout[0] = gin[0];
  const float* pp = part + (long)b * 524288 + i * 128 + t;
  float s = 0.f;
#pragma unroll
  for (int c = 0; c < 32; ++c) s += pp[(long)c * 16384];
  att[((long)b * 128 + i) * 128 + t] = s;
}

// ---------------------------------------------------------------------------
// softmax2: in-place column softmax (over i) of S in the attn segment.
// ---------------------------------------------------------------------------
__global__ __launch_bounds__(256) void softmax2(float* __restrict__ att) {
  __shared__ float red[16][17];
  const int b = blockIdx.y, c0 = blockIdx.x * 16;
  const int t = threadIdx.x, col = t & 15, ig = t >> 4;
  float* ab = att + (long)b * 16384 + c0 + col;
  float s[8];
  float m = -3.0e38f;
#pragma unroll
  for (int j = 0; j < 8; ++j) {
    s[j] = ab[(ig * 8 + j) * 128];
    m = fmaxf(m, s[j]);
  }
  red[ig][col] = m;
  __syncthreads();
  float mx = red[0][col];
#pragma unroll
  for (int k = 1; k < 16; ++k) mx = fmaxf(mx, red[k][col]);
  float sum = 0.f;
#pragma unroll
  for (int j = 0; j < 8; ++j) {
    s[j] = expf(s[j] - mx);
    sum += s[j];
  }
  __syncthreads();
  red[ig][col] = sum;
  __syncthreads();
  float tot = 0.f;
#pragma unroll
  for (int k = 0; k < 16; ++k) tot += red[k][col];
  float inv = 1.f / tot;
#pragma unroll
  for (int j = 0; j < 8; ++j) ab[(ig * 8 + j) * 128] = s[j] * inv;
}

// ---------------------------------------------------------------------------
// pvf_fused: out1+final fused per (b, h).  (unchanged from round 7)
// ---------------------------------------------------------------------------
__global__ __launch_bounds__(256, 2) void pvf_fused(
    const float* __restrict__ vseg, const float* __restrict__ att,
    const char* __restrict__ wu, const float* __restrict__ bup,
    float* __restrict__ oseg) {
  __shared__ char attnT[128 * 272];  // [w][136 f16] = attn^T
  __shared__ char vA[64 * 272];      // [c' chunk][136 f16]
  __shared__ char HT[128 * 144];     // [w][72 f16] = H'^T chunk
  const int t = threadIdx.x, lane = t & 63, w = t >> 6;
  const int l15 = lane & 15, g = lane >> 4;
  const int b = blockIdx.y, h = blockIdx.x;
  const float* ab = att + (long)b * 16384;
  const float* vb = vseg + (long)b * PB;
  float* Ob = oseg + (long)b * PB;

#pragma unroll
  for (int it = 0; it < 4; ++it) {
    const int f = t + 256 * it;       // 1024 = 32 i4 x 32 w4
    const int i4 = f >> 5, w4 = f & 31;
    const float4 r0 = *(const float4*)(ab + (4 * i4 + 0) * 128 + 4 * w4);
    const float4 r1 = *(const float4*)(ab + (4 * i4 + 1) * 128 + 4 * w4);
    const float4 r2 = *(const float4*)(ab + (4 * i4 + 2) * 128 + 4 * w4);
    const float4 r3 = *(const float4*)(ab + (4 * i4 + 3) * 128 + 4 * w4);
    *(uint2*)(attnT + (4 * w4 + 0) * 272 + swz(4 * w4 + 0, 8 * i4)) =
        make_uint2(pk2(r0.x, r1.x), pk2(r2.x, r3.x));
    *(uint2*)(attnT + (4 * w4 + 1) * 272 + swz(4 * w4 + 1, 8 * i4)) =
        make_uint2(pk2(r0.y, r1.y), pk2(r2.y, r3.y));
    *(uint2*)(attnT + (4 * w4 + 2) * 272 + swz(4 * w4 + 2, 8 * i4)) =
        make_uint2(pk2(r0.z, r1.z), pk2(r2.z, r3.z));
    *(uint2*)(attnT + (4 * w4 + 3) * 272 + swz(4 * w4 + 3, 8 * i4)) =
        make_uint2(pk2(r0.w, r1.w), pk2(r2.w, r3.w));
  }

  f32x4 acc2[4][8] = {};  // G2: o = w*64+16mf+4g+r, w' = 16nf+l15

  for (int cc = 0; cc < 4; ++cc) {
#pragma unroll
    for (int it = 0; it < 8; ++it) {
      const int f = t + 256 * it;     // 2048 = 64 rows x 32 float4
      const int cp = f >> 5, q4 = f & 31;
      const float4 v4 =
          *(const float4*)(vb + ((long)(cc * 64 + cp) * 128 + h) * 128 + 4 * q4);
      *(uint2*)(vA + cp * 272 + swz(cp, 8 * q4)) =
          make_uint2(pk2(v4.x, v4.y), pk2(v4.z, v4.w));
    }
    __syncthreads();

    f32x4 acc1[8] = {};
#pragma unroll
    for (int kf = 0; kf < 4; ++kf) {
      const f16x8 a = ldfrag((const f16*)vA, 272, w * 16 + l15, 64 * kf + 16 * g);
#pragma unroll
      for (int nf = 0; nf < 8; ++nf) {
        const f16x8 bf = ldfrag((const f16*)attnT, 272, 16 * nf + l15, 64 * kf + 16 * g);
        acc1[nf] = mfma16(a, bf, acc1[nf]);
      }
    }
#pragma unroll
    for (int nf = 0; nf < 8; ++nf)
#pragma unroll
      for (int r = 0; r < 4; ++r) {
        const int wp = 16 * nf + l15;
        const int cp = w * 16 + 4 * g + r;
        *(f16*)(HT + wp * 144 + swz(wp, 2 * cp)) = (f16)acc1[nf][r];
      }
    __syncthreads();

#pragma unroll
    for (int kf2 = 0; kf2 < 2; ++kf2) {
      const char* WU = wu + (long)(cc * 2 + kf2) * 16384;
      f16x8 af[4];
#pragma unroll
      for (int mf = 0; mf < 4; ++mf)
        af[mf] = ld64(WU, w * 64 + 16 * mf + l15, g);
#pragma unroll
      for (int nf = 0; nf < 8; ++nf) {
        const f16x8 bf = ldfrag((const f16*)HT, 144, 16 * nf + l15, 64 * kf2 + 16 * g);
#pragma unroll
        for (int mf = 0; mf < 4; ++mf)
          acc2[mf][nf] = mfma16(af[mf], bf, acc2[mf][nf]);
      }
    }
  }

#pragma unroll
  for (int mf = 0; mf < 4; ++mf)
#pragma unroll
    for (int nf = 0; nf < 8; ++nf)
#pragma unroll
      for (int r = 0; r < 4; ++r) {
        const int o = w * 64 + 16 * mf + 4 * g + r;
        const int wp = 16 * nf + l15;
        Ob[(long)o * HW + h * 128 + wp] = acc2[mf][nf][r] + bup[o];
      }
}

// ---------------------------------------------------------------------------
// Fallback kernels (used only if ws_size < WS_NEED).
// ---------------------------------------------------------------------------
__global__ __launch_bounds__(128) void softmax_kernel(
    const float* __restrict__ part, float* __restrict__ att,
    float* __restrict__ gout, const float* __restrict__ gin) {
  const int b = blockIdx.x, t = threadIdx.x;
  if (b == 0 && t == 0) gout[0] = gin[0];
  const float* pp = part + (long)b * 32 * 16384;
  float* ab = att + (long)b * 16384;
  float mx = -3.0e38f;
  for (int i = 0; i < 128; ++i) {
    float s = 0.f;
#pragma unroll
    for (int c = 0; c < 32; ++c) s += pp[(long)c * 16384 + i * 128 + t];
    ab[i * 128 + t] = s;
    mx = fmaxf(mx, s);
  }
  float sum = 0.f;
  for (int i = 0; i < 128; ++i) {
    float e = expf(ab[i * 128 + t] - mx);
    sum += e;
    ab[i * 128 + t] = e;
  }
  float inv = 1.f / sum;
  for (int i = 0; i < 128; ++i) ab[i * 128 + t] *= inv;
}

template <int MODE>
__global__ __launch_bounds__(256) void proj_kernel(
    const float* __restrict__ x, const float* __restrict__ Wm,
    float* __restrict__ out) {
  constexpr int SB = 80;
  __shared__ f16 Wh[256 * 40];
  __shared__ f16 Wl[256 * 40];
  __shared__ f16 Xh[64 * 40];
  __shared__ f16 Xl[64 * 40];

  const int t = threadIdx.x;
  const int lane = t & 63;
  const int w = t >> 6;
  const int l15 = lane & 15;
  const int g = lane >> 4;
  const int b = blockIdx.y;
  const int hw0 = blockIdx.x * 64;
  const float* xb = x + (long)b * PB;

  f32x4 acc[4][4] = {};

  for (int kc = 0; kc < 256; kc += 32) {
#pragma unroll
    for (int it = 0; it < 8; ++it) {
      int f4 = t + 256 * it;
      int o = f4 >> 3, c4 = f4 & 7;
      float4 v = *(const float4*)(Wm + o * 256 + kc + 4 * c4);
      unsigned h01, l01, h23, l23;
      split_pk2(v.x, v.y, h01, l01);
      split_pk2(v.z, v.w, h23, l23);
      int kb = swz(o, 8 * c4);
      *(uint2*)((char*)Wh + o * SB + kb) = make_uint2(h01, h23);
      *(uint2*)((char*)Wl + o * SB + kb) = make_uint2(l01, l23);
    }
    {
      int c = t & 63, rq = t >> 6;
      float vs[8];
#pragma unroll
      for (int r = 0; r < 8; ++r)
        vs[r] = xb[(long)(kc + 8 * rq + r) * HW + hw0 + c];
#pragma unroll
      for (int u = 0; u < 2; ++u) {
        unsigned h0, l0, h1, l1;
        split_pk2(vs[4 * u], vs[4 * u + 1], h0, l0);
        split_pk2(vs[4 * u + 2], vs[4 * u + 3], h1, l1);
        int kb = swz(c, 16 * rq + 8 * u);
        *(uint2*)((char*)Xh + c * SB + kb) = make_uint2(h0, h1);
        *(uint2*)((char*)Xl + c * SB + kb) = make_uint2(l0, l1);
      }
    }
    __syncthreads();

    f16x8 wfh[4], wfl[4], xfh[4], xfl[4];
#pragma unroll
    for (int f = 0; f < 4; ++f) {
      int wr = 64 * w + 16 * f + l15;
      int xr = 16 * f + l15;
      wfh[f] = ldfrag(Wh, SB, wr, 16 * g);
      wfl[f] = ldfrag(Wl, SB, wr, 16 * g);
      xfh[f] = ldfrag(Xh, SB, xr, 16 * g);
      xfl[f] = ldfrag(Xl, SB, xr, 16 * g);
    }
#pragma unroll
    for (int mf = 0; mf < 4; ++mf)
#pragma unroll
      for (int nf = 0; nf < 4; ++nf) {
        if constexpr (MODE == 0) {
          acc[mf][nf] = mfma16(wfh[mf], xfh[nf], acc[mf][nf]);
          acc[mf][nf] = mfma16(wfh[mf], xfl[nf], acc[mf][nf]);
          acc[mf][nf] = mfma16(wfl[mf], xfh[nf], acc[mf][nf]);
        } else {
          acc[mf][nf] = mfma16(xfh[mf], wfh[nf], acc[mf][nf]);
          acc[mf][nf] = mfma16(xfh[mf], wfl[nf], acc[mf][nf]);
          acc[mf][nf] = mfma16(xfl[mf], wfh[nf], acc[mf][nf]);
        }
      }
    __syncthreads();
  }

  float* ob = out + (long)b * PB;
#pragma unroll
  for (int mf = 0; mf < 4; ++mf)
#pragma unroll
    for (int nf = 0; nf < 4; ++nf)
#pragma unroll
      for (int r = 0; r < 4; ++r) {
        float v = acc[mf][nf][r];
        v = v > 0.f ? v : 0.f;
        if constexpr (MODE == 0) {
          int o = 64 * w + 16 * mf + 4 * g + r;
          int hw = hw0 + 16 * nf + l15;
          ob[(long)o * HW + hw] = v;
        } else {
          int hw = hw0 + 16 * mf + 4 * g + r;
          int o = 64 * w + 16 * nf + l15;
          ob[((o & 1) ? HALF : 0) + (long)hw * 128 + (o >> 1)] = v;
        }
      }
}

__global__ __launch_bounds__(256) void out1_fb(
    const float* __restrict__ vseg, const float* __restrict__ att,
    float* __restrict__ outseg) {
  constexpr int SB = 272;
  __shared__ f16 Va[64 * 136], Ba[128 * 136];
  const int t = threadIdx.x, lane = t & 63, w = t >> 6;
  const int l15 = lane & 15, g = lane >> 4;
  const int b = blockIdx.y;
  const long j0 = (long)blockIdx.x * 64;
  const float* vb = vseg + (long)b * PB + j0 * 128;
  const float* ab = att + (long)b * 16384;

#pragma unroll
  for (int it = 0; it < 8; ++it) {
    int f4 = t + 256 * it;
    int j = f4 >> 5, c4 = f4 & 31;
    float4 v = *(const float4*)(vb + (long)j * 128 + 4 * c4);
    int kb = swz(j, 8 * c4);
    *(uint2*)((char*)Va + j * SB + kb) = make_uint2(pk2(v.x, v.y), pk2(v.z, v.w));
  }
  {
    int c = t & 127, rh = t >> 7;
#pragma unroll
    for (int uu = 0; uu < 16; ++uu) {
      int i0 = 64 * rh + 4 * uu;
      float v0 = ab[(i0 + 0) * 128 + c];
      float v1 = ab[(i0 + 1) * 128 + c];
      float v2 = ab[(i0 + 2) * 128 + c];
      float v3 = ab[(i0 + 3) * 128 + c];
      int kb = swz(c, 2 * i0);
      *(uint2*)((char*)Ba + c * SB + kb) = make_uint2(pk2(v0, v1), pk2(v2, v3));
    }
  }
  __syncthreads();

  f32x4 acc[2][4] = {};
#pragma unroll
  for (int kf = 0; kf < 4; ++kf) {
    f16x8 af[2], bf[4];
#pragma unroll
    for (int mf = 0; mf < 2; ++mf)
      af[mf] = ldfrag(Va, SB, (w & 1) * 32 + 16 * mf + l15, 64 * kf + 16 * g);
#pragma unroll
    for (int nf = 0; nf < 4; ++nf)
      bf[nf] = ldfrag(Ba, SB, (w >> 1) * 64 + 16 * nf + l15, 64 * kf + 16 * g);
#pragma unroll
    for (int mf = 0; mf < 2; ++mf)
#pragma unroll
      for (int nf = 0; nf < 4; ++nf)
        acc[mf][nf] = mfma16(af[mf], bf[nf], acc[mf][nf]);
  }

  float* ob = outseg + (long)b * PB;
#pragma unroll
  for (int mf = 0; mf < 2; ++mf)
#pragma unroll
    for (int nf = 0; nf < 4; ++nf)
#pragma unroll
      for (int r = 0; r < 4; ++r) {
        long j = j0 + (w & 1) * 32 + 16 * mf + 4 * g + r;
        int i2 = (w >> 1) * 64 + 16 * nf + l15;
        ob[j * 128 + i2] = acc[mf][nf][r];
      }
}

__global__ __launch_bounds__(256) void final_kernel(
    float* __restrict__ outseg, const float* __restrict__ Wup,
    const float* __restrict__ bup, const float* __restrict__ gin) {
  constexpr int SB = 144;
  __shared__ f16 Ah[256 * 72], Bh[64 * 72];
  const int t = threadIdx.x, lane = t & 63, w = t >> 6;
  const int l15 = lane & 15, g = lane >> 4;
  const int b = blockIdx.y;
  const int hw0 = blockIdx.x * 64;
  const float gamma = gin[0];
  float* Hb = outseg + (long)b * PB;

  f32x4 acc[4][4] = {};

  for (int kc = 0; kc < 256; kc += 64) {
#pragma unroll
    for (int it = 0; it < 16; ++it) {
      int f4 = t + 256 * it;
      int o = f4 >> 4, c4 = f4 & 15;
      float4 v = *(const float4*)(Wup + o * 256 + kc + 4 * c4);
      int kb = swz(o, 8 * c4);
      *(uint2*)((char*)Ah + o * SB + kb) =
          make_uint2(pk2(v.x * gamma, v.y * gamma), pk2(v.z * gamma, v.w * gamma));
    }
    {
      int n = t & 63, rq = t >> 6;
#pragma unroll
      for (int uu = 0; uu < 4; ++uu) {
        int r0 = 16 * rq + 4 * uu;
        float v0 = Hb[(long)(kc + r0 + 0) * HW + hw0 + n];
        float v1 = Hb[(long)(kc + r0 + 1) * HW + hw0 + n];
        float v2 = Hb[(long)(kc + r0 + 2) * HW + hw0 + n];
        float v3 = Hb[(long)(kc + r0 + 3) * HW + hw0 + n];
        int kb = swz(n, 2 * r0);
        *(uint2*)((char*)Bh + n * SB + kb) = make_uint2(pk2(v0, v1), pk2(v2, v3));
      }
    }
    __syncthreads();

    f16x8 af[4][2], bf[4][2];
#pragma unroll
    for (int f = 0; f < 4; ++f)
#pragma unroll
      for (int kf = 0; kf < 2; ++kf) {
        af[f][kf] = ldfrag(Ah, SB, 64 * w + 16 * f + l15, 64 * kf + 16 * g);
        bf[f][kf] = ldfrag(Bh, SB, 16 * f + l15, 64 * kf + 16 * g);
      }
#pragma unroll
    for (int mf = 0; mf < 4; ++mf)
#pragma unroll
      for (int nf = 0; nf < 4; ++nf) {
        acc[mf][nf] = mfma16(af[mf][0], bf[nf][0], acc[mf][nf]);
        acc[mf][nf] = mfma16(af[mf][1], bf[nf][1], acc[mf][nf]);
      }
    __syncthreads();
  }

#pragma unroll
  for (int mf = 0; mf < 4; ++mf)
#pragma unroll
    for (int nf = 0; nf < 4; ++nf)
#pragma unroll
      for (int r = 0; r < 4; ++r) {
        int o = 64 * w + 16 * mf + 4 * g + r;
        int hw = hw0 + 16 * nf + l15;
        Hb[(long)o * HW + hw] = acc[mf][nf][r] + bup[o];
      }
}

// ---------------------------------------------------------------------------
extern "C" void kernel_launch(void* const* d_in, const int* in_sizes, int n_in,
                              void* d_out, int out_size, void* d_ws, size_t ws_size,
                              hipStream_t stream) {
  (void)in_sizes; (void)n_in; (void)out_size;

  const float* x  = (const float*)d_in[0];
  const float* Wq = (const float*)d_in[1];
  const float* Wk = (const float*)d_in[2];
  const float* Wv = (const float*)d_in[3];
  const float* gm = (const float*)d_in[4];
  const float* Wu = (const float*)d_in[5];
  const float* bu = (const float*)d_in[6];

  float* out  = (float*)d_out;
  float* oseg = out;                 // [B,256,128,128] final (scratch first)
  float* qseg = out + 67108864L;     // [B,128,32768]
  float* kseg = out + 134217728L;    // [B,32768,128]
  float* vseg = out + 201326592L;    // [B,32768,128]
  float* gseg = out + 268435456L;    // [1]
  float* aseg = out + 268435457L;    // [B,128,128]

  dim3 blk(256);
  if (ws_size >= (size_t)WS_NEED && d_ws != nullptr) {
    char* ws = (char*)d_ws;
    prep_w<<<dim3(8, 4), blk, 0, stream>>>(Wq, Wk, Wv, Wu, gm, ws);
    qkv_fused3<<<dim3(256, 16), blk, 0, stream>>>(
        x, ws + WH_OFF, ws + WL_OFF, ws + WH_OFF + 131072, ws + WL_OFF + 131072,
        ws + WH_OFF + 262144, qseg, kseg, vseg);
    spart2<<<dim3(32, 16), blk, 0, stream>>>(qseg, kseg, oseg);
    reduce_s<<<dim3(128, 16), dim3(128), 0, stream>>>(oseg, aseg, gseg, gm);
    softmax2<<<dim3(8, 16), blk, 0, stream>>>(aseg);
    pvf_fused<<<dim3(128, 16), blk, 0, stream>>>(vseg, aseg, ws + WU_OFF, bu, oseg);
  } else {
    proj_kernel<0><<<dim3(256, 16), blk, 0, stream>>>(x, Wq, qseg);
    proj_kernel<1><<<dim3(256, 16), blk, 0, stream>>>(x, Wk, kseg);
    proj_kernel<1><<<dim3(256, 16), blk, 0, stream>>>(x, Wv, vseg);
    spart2<<<dim3(32, 16), blk, 0, stream>>>(qseg, kseg, oseg);
    softmax_kernel<<<dim3(16), dim3(128), 0, stream>>>(oseg, aseg, gseg, gm);
    out1_fb<<<dim3(512, 16), blk, 0, stream>>>(vseg, aseg, oseg);
    final_kernel<<<dim3(256, 16), blk, 0, stream>>>(oseg, Wu, bu, gm);
  }
}

// Round 9
// 633.358 us; speedup vs baseline: 1.0730x; 1.0730x over previous
//
#include <hip/hip_runtime.h>
#include <stdint.h>

// ---------------------------------------------------------------------------
// Axis_Horizontal_Attention, MI355X (gfx950).  B=16, C=256, H=W=128, fp32.
// Round 9: qkv_fused4 -- 512-thread blocks on the same 64-hw tile (64 KB LDS,
// 2 blocks/CU -> 4 waves/SIMD, double the latency hiding), wave tiles 32x64 /
// 64x32 with disjoint per-wave W rows.  spart reverted to the round-7
// known-good version.  Everything else unchanged from round 7.
// ---------------------------------------------------------------------------

typedef _Float16 f16;
typedef __attribute__((ext_vector_type(8))) _Float16 f16x8;
typedef __attribute__((ext_vector_type(4))) float f32x4;

#define DEV static __device__ __forceinline__

constexpr int  HW   = 16384;     // H*W
constexpr long PB   = 4194304;   // C*H*W per batch
constexpr long HALF = 2097152;   // HW*128

// ws layout (bytes): W images only (~0.9 MB)
constexpr long WH_OFF  = 0;                      // [3][8][256][64B]
constexpr long WL_OFF  = 393216;
constexpr long WU_OFF  = 786432;                 // [8][256][64B], gamma-folded
constexpr long WS_NEED = 1048576;

DEV unsigned pk2(float a, float b) {
  auto h = __builtin_amdgcn_cvt_pkrtz(a, b);
  return __builtin_bit_cast(unsigned, h);
}
DEV void split_pk2(float a, float b, unsigned& hu, unsigned& lu) {
  auto h = __builtin_amdgcn_cvt_pkrtz(a, b);
  auto l = __builtin_amdgcn_cvt_pkrtz(a - (float)h[0], b - (float)h[1]);
  hu = __builtin_bit_cast(unsigned, h);
  lu = __builtin_bit_cast(unsigned, l);
}
DEV f32x4 mfma16(f16x8 a, f16x8 b, f32x4 c) {
  return __builtin_amdgcn_mfma_f32_16x16x32_f16(a, b, c, 0, 0, 0);
}
// 64B-row image layout, granule swizzle; works for LDS and global pointers.
DEV f16x8 ld64(const char* base, int row, int g) {
  return *(const f16x8*)(base + row * 64 + 16 * (g ^ ((row >> 1) & 3)));
}

DEV void gload16(const void* g, void* l) {
  __builtin_amdgcn_global_load_lds(
      (const __attribute__((address_space(1))) uint32_t*)(g),
      (__attribute__((address_space(3))) uint32_t*)(l), 16, 0, 0);
}

// generic padded-row LDS frag helpers
DEV int swz(int row, int kbyte) {
  return (kbyte & ~63) | ((kbyte & 63) ^ (((row >> 3) & 3) << 4));
}
DEV f16x8 ldfrag(const f16* arr, int strideB, int row, int kbyte) {
  return *(const f16x8*)((const char*)arr + row * strideB + swz(row, kbyte));
}

// ---------------------------------------------------------------------------
// prepass W: split Wq/Wk/Wv (hi/lo) and gamma*Wup (hi) into swizzled
// image layout.  grid (8 kc, 4 m), block 256 (thread = o row).
// ---------------------------------------------------------------------------
__global__ __launch_bounds__(256) void prep_w(
    const float* __restrict__ Wq, const float* __restrict__ Wk,
    const float* __restrict__ Wv, const float* __restrict__ Wu,
    const float* __restrict__ gin, char* __restrict__ ws) {
  const int kc = blockIdx.x, m = blockIdx.y, o = threadIdx.x;
  const float* src = (m == 0) ? Wq : (m == 1) ? Wk : (m == 2) ? Wv : Wu;
  const float sc = (m == 3) ? gin[0] : 1.0f;
  float v[32];
#pragma unroll
  for (int j = 0; j < 32; ++j) v[j] = src[o * 256 + kc * 32 + j] * sc;
  char* dh = (m < 3) ? (ws + WH_OFF + ((long)(m * 8 + kc) * 256 + o) * 64)
                     : (ws + WU_OFF + ((long)kc * 256 + o) * 64);
  char* dl = ws + WL_OFF + ((long)(m * 8 + kc) * 256 + o) * 64;
  const int sw = (o >> 1) & 3;
#pragma unroll
  for (int gq = 0; gq < 4; ++gq) {
    unsigned h[4], l[4];
#pragma unroll
    for (int p = 0; p < 4; ++p)
      split_pk2(v[8 * gq + 2 * p], v[8 * gq + 2 * p + 1], h[p], l[p]);
    const int off = 16 * (gq ^ sw);
    *(uint4*)(dh + off) = make_uint4(h[0], h[1], h[2], h[3]);
    if (m < 3) *(uint4*)(dl + off) = make_uint4(l[0], l[1], l[2], l[3]);
  }
}

// ---------------------------------------------------------------------------
// qkv_fused4: relu(Wq@X), relu(Wk@X), relu(Wv@X) for one (b, 64-hw) slice.
// Block 512 thr (8 waves), 64 KB LDS -> 2 blocks/CU -> 4 waves/SIMD.
// Wave tiles: q 32o x 64hw (acc[2][4]); k/v 64hw x 32o (acc[4][2]).
// Per-wave W rows disjoint (no redundant L2 fragment loads).
// k/v epilogues repacked through LDS into coalesced 512B row writes.
// grid (256, 16).
// ---------------------------------------------------------------------------
__global__ __launch_bounds__(512, 4) void qkv_fused4(
    const float* __restrict__ x,
    const char* __restrict__ wqh, const char* __restrict__ wql,
    const char* __restrict__ wkh, const char* __restrict__ wkl,
    const char* __restrict__ wvh,
    float* __restrict__ qseg, float* __restrict__ kseg,
    float* __restrict__ vseg) {
  __shared__ char lds[65536];
  char* Xh = lds;              // [8 kc][64 hw][64B]
  char* Xl = lds + 32768;
  float* R = (float*)(lds + 32768);  // repack buffer, reuses Xl after k MFMA
  const int t = threadIdx.x, lane = t & 63, w = t >> 6;  // w in [0,8)
  const int l15 = lane & 15, g = lane >> 4;
  const int b = blockIdx.y, hw0 = blockIdx.x * 64;
  const float* xb = x + (long)b * PB + hw0;

  // ---- stage: x slice [256 c][64 hw] -> transpose + hi/lo split into LDS
  {
    const int hw = t & 63, cq = t >> 6;  // cq in [0,8): 32 c's each
    const int sw = (hw >> 1) & 3;
#pragma unroll
    for (int j8 = 0; j8 < 4; ++j8) {
      const int c0 = cq * 32 + j8 * 8;
      float v[8];
#pragma unroll
      for (int i = 0; i < 8; ++i) v[i] = xb[(long)(c0 + i) * HW + hw];
      unsigned h[4], l[4];
#pragma unroll
      for (int p = 0; p < 4; ++p)
        split_pk2(v[2 * p], v[2 * p + 1], h[p], l[p]);
      const int kc = cq, gi = j8;
      const int off = kc * 4096 + hw * 64 + 16 * (gi ^ sw);
      *(uint4*)(Xh + off) = make_uint4(h[0], h[1], h[2], h[3]);
      *(uint4*)(Xl + off) = make_uint4(l[0], l[1], l[2], l[3]);
    }
  }
  __syncthreads();  // X image ready; LDS read-only hereafter

  // transposed-output repack for k/v (acc[4][2]: hw=16mf+4g+r, o=w*32+16nf+l15)
  auto repack_store = [&](f32x4 (&ac)[4][2], float* ob) {
#pragma unroll
    for (int half = 0; half < 2; ++half) {
#pragma unroll
      for (int mf2 = 0; mf2 < 2; ++mf2) {
        const int mf = 2 * half + mf2;
#pragma unroll
        for (int nf = 0; nf < 2; ++nf)
#pragma unroll
          for (int r = 0; r < 4; ++r) {
            const int hwloc = 16 * mf2 + 4 * g + r;
            const int o = w * 32 + 16 * nf + l15;
            const int col = (o >> 1) ^ (((hwloc >> 2) & 3) << 3);
            float v = ac[mf][nf][r];
            R[(o & 1) * 4096 + hwloc * 128 + col] = v > 0.f ? v : 0.f;
          }
      }
      __syncthreads();
#pragma unroll
      for (int it = 0; it < 4; ++it) {
        const int f = t + 512 * it;  // [2 parity][32 hwloc][32 q4]
        const int parity = f >> 10, hwloc = (f >> 5) & 31, q4 = f & 31;
        const int col = (4 * q4) ^ (((hwloc >> 2) & 3) << 3);
        const float4 v4 = *(const float4*)(R + parity * 4096 + hwloc * 128 + col);
        *(float4*)(ob + (long)parity * HALF +
                   (long)(hw0 + 32 * half + hwloc) * 128 + 4 * q4) = v4;
      }
      __syncthreads();
    }
  };

  // ---- q pass: A = Wq rows [w*32, w*32+32) (L2 frags), B = X (LDS).
  {
    f32x4 acc[2][4] = {};
    for (int kc = 0; kc < 8; ++kc) {
      const char* XH = Xh + kc * 4096;
      const char* XL = Xl + kc * 4096;
      const char* WH = wqh + (long)kc * 16384;
      const char* WL = wql + (long)kc * 16384;
      f16x8 bh[4], bl[4];
#pragma unroll
      for (int nf = 0; nf < 4; ++nf) {
        bh[nf] = ld64(XH, 16 * nf + l15, g);
        bl[nf] = ld64(XL, 16 * nf + l15, g);
      }
#pragma unroll
      for (int mf = 0; mf < 2; ++mf) {
        const int orow = w * 32 + 16 * mf + l15;
        f16x8 ah = ld64(WH, orow, g);
        f16x8 al = ld64(WL, orow, g);
#pragma unroll
        for (int nf = 0; nf < 4; ++nf) {
          acc[mf][nf] = mfma16(ah, bh[nf], acc[mf][nf]);
          acc[mf][nf] = mfma16(ah, bl[nf], acc[mf][nf]);
          acc[mf][nf] = mfma16(al, bh[nf], acc[mf][nf]);
        }
      }
    }
    float* ob = qseg + (long)b * PB;
#pragma unroll
    for (int mf = 0; mf < 2; ++mf)
#pragma unroll
      for (int nf = 0; nf < 4; ++nf)
#pragma unroll
        for (int r = 0; r < 4; ++r) {
          float v = acc[mf][nf][r];
          v = v > 0.f ? v : 0.f;
          const int o = w * 32 + 16 * mf + 4 * g + r;
          const int hw = hw0 + 16 * nf + l15;
          ob[(long)o * HW + hw] = v;
        }
  }

  // ---- k pass: A = X (LDS), B = Wk rows [w*32, w*32+32).
  {
    f32x4 acc[4][2] = {};
    for (int kc = 0; kc < 8; ++kc) {
      const char* XH = Xh + kc * 4096;
      const char* XL = Xl + kc * 4096;
      const char* WH = wkh + (long)kc * 16384;
      const char* WL = wkl + (long)kc * 16384;
      f16x8 bh[2], bl[2];
#pragma unroll
      for (int nf = 0; nf < 2; ++nf) {
        const int orow = w * 32 + 16 * nf + l15;
        bh[nf] = ld64(WH, orow, g);
        bl[nf] = ld64(WL, orow, g);
      }
#pragma unroll
      for (int mf = 0; mf < 4; ++mf) {
        f16x8 ah = ld64(XH, 16 * mf + l15, g);
        f16x8 al = ld64(XL, 16 * mf + l15, g);
#pragma unroll
        for (int nf = 0; nf < 2; ++nf) {
          acc[mf][nf] = mfma16(ah, bh[nf], acc[mf][nf]);
          acc[mf][nf] = mfma16(ah, bl[nf], acc[mf][nf]);
          acc[mf][nf] = mfma16(al, bh[nf], acc[mf][nf]);
        }
      }
    }
    __syncthreads();  // all Xl reads complete before R overwrites it
    repack_store(acc, kseg + (long)b * PB);
  }

  // ---- v pass: hi-only.  A = Xh (LDS), B = Wv-hi rows [w*32, w*32+32).
  {
    f32x4 acc[4][2] = {};
    for (int kc = 0; kc < 8; ++kc) {
      const char* XH = Xh + kc * 4096;
      const char* WH = wvh + (long)kc * 16384;
      f16x8 bh[2];
#pragma unroll
      for (int nf = 0; nf < 2; ++nf)
        bh[nf] = ld64(WH, w * 32 + 16 * nf + l15, g);
#pragma unroll
      for (int mf = 0; mf < 4; ++mf) {
        f16x8 ah = ld64(XH, 16 * mf + l15, g);
#pragma unroll
        for (int nf = 0; nf < 2; ++nf)
          acc[mf][nf] = mfma16(ah, bh[nf], acc[mf][nf]);
      }
    }
    repack_store(acc, vseg + (long)b * PB);
  }
}

// ---------------------------------------------------------------------------
// spart: S partials, K-split 32 chunks.  (round-7 known-good version)
// ---------------------------------------------------------------------------
__global__ __launch_bounds__(256) void spart_kernel(
    const float* __restrict__ qseg, const float* __restrict__ kseg,
    float* __restrict__ part) {
  constexpr int SB = 80;
  __shared__ f16 Ah[128 * 40], Al[128 * 40], Bh[128 * 40], Bl[128 * 40];
  const int t = threadIdx.x, lane = t & 63, w = t >> 6;
  const int l15 = lane & 15, g = lane >> 4;
  const int ch = blockIdx.x, b = blockIdx.y;
  const float* qb = qseg + (long)b * PB + ch * 1024;
  const float* kb = kseg + (long)b * PB + (long)ch * 1024 * 128;

  f32x4 acc[4][4] = {};

  for (int kc = 0; kc < 1024; kc += 32) {
#pragma unroll
    for (int it = 0; it < 4; ++it) {
      int f4 = t + 256 * it;
      int i = f4 >> 3, c4 = f4 & 7;
      float4 v = *(const float4*)(qb + (long)i * 32768 + kc + 4 * c4);
      unsigned h01, l01, h23, l23;
      split_pk2(v.x, v.y, h01, l01);
      split_pk2(v.z, v.w, h23, l23);
      int kbo = swz(i, 8 * c4);
      *(uint2*)((char*)Ah + i * SB + kbo) = make_uint2(h01, h23);
      *(uint2*)((char*)Al + i * SB + kbo) = make_uint2(l01, l23);
    }
    {
      int c = t & 127, rh = t >> 7;
      float vs[16];
#pragma unroll
      for (int r = 0; r < 16; ++r)
        vs[r] = kb[(long)(kc + 16 * rh + r) * 128 + c];
#pragma unroll
      for (int u = 0; u < 4; ++u) {
        unsigned h0, l0, h1, l1;
        split_pk2(vs[4 * u], vs[4 * u + 1], h0, l0);
        split_pk2(vs[4 * u + 2], vs[4 * u + 3], h1, l1);
        int kbo = swz(c, 32 * rh + 8 * u);
        *(uint2*)((char*)Bh + c * SB + kbo) = make_uint2(h0, h1);
        *(uint2*)((char*)Bl + c * SB + kbo) = make_uint2(l0, l1);
      }
    }
    __syncthreads();

    f16x8 afh[4], afl[4], bfh[4], bfl[4];
#pragma unroll
    for (int f = 0; f < 4; ++f) {
      int ar = (w & 1) * 64 + 16 * f + l15;
      int br = (w >> 1) * 64 + 16 * f + l15;
      afh[f] = ldfrag(Ah, SB, ar, 16 * g);
      afl[f] = ldfrag(Al, SB, ar, 16 * g);
      bfh[f] = ldfrag(Bh, SB, br, 16 * g);
      bfl[f] = ldfrag(Bl, SB, br, 16 * g);
    }
#pragma unroll
    for (int mf = 0; mf < 4; ++mf)
#pragma unroll
      for (int nf = 0; nf < 4; ++nf) {
        acc[mf][nf] = mfma16(afh[mf], bfh[nf], acc[mf][nf]);
        acc[mf][nf] = mfma16(afh[mf], bfl[nf], acc[mf][nf]);
        acc[mf][nf] = mfma16(afl[mf], bfh[nf], acc[mf][nf]);
      }
    __syncthreads();
  }

  float* pp = part + (long)(b * 32 + ch) * 16384;
#pragma unroll
  for (int mf = 0; mf < 4; ++mf)
#pragma unroll
    for (int nf = 0; nf < 4; ++nf)
#pragma unroll
      for (int r = 0; r < 4; ++r) {
        int i = (w & 1) * 64 + 16 * mf + 4 * g + r;
        int i2 = (w >> 1) * 64 + 16 * nf + l15;
        pp[i * 128 + i2] = acc[mf][nf][r];
      }
}

// ---------------------------------------------------------------------------
// reduce_s: sum 32 partial S chunks -> S (into attn segment) + gamma.
// ---------------------------------------------------------------------------
__global__ __launch_bounds__(128) void reduce_s(
    const float* __restrict__ part, float* __restrict__ att,
    float* __restrict__ gout, const float* __restrict__ gin) {
  const int i = blockIdx.x, b = blockIdx.y, t = threadIdx.x;
  if (b == 0 && i == 0 && t == 0) gout[0] = gin[0];
  const float* pp = part + (long)b * 524288 + i * 128 + t;
  float s = 0.f;
#pragma unroll
  for (int c = 0; c < 32; ++c) s += pp[(long)c * 16384];
  att[((long)b * 128 + i) * 128 + t] = s;
}

// ---------------------------------------------------------------------------
// softmax2: in-place column softmax (over i) of S in the attn segment.
// ---------------------------------------------------------------------------
__global__ __launch_bounds__(256) void softmax2(float* __restrict__ att) {
  __shared__ float red[16][17];
  const int b = blockIdx.y, c0 = blockIdx.x * 16;
  const int t = threadIdx.x, col = t & 15, ig = t >> 4;
  float* ab = att + (long)b * 16384 + c0 + col;
  float s[8];
  float m = -3.0e38f;
#pragma unroll
  for (int j = 0; j < 8; ++j) {
    s[j] = ab[(ig * 8 + j) * 128];
    m = fmaxf(m, s[j]);
  }
  red[ig][col] = m;
  __syncthreads();
  float mx = red[0][col];
#pragma unroll
  for (int k = 1; k < 16; ++k) mx = fmaxf(mx, red[k][col]);
  float sum = 0.f;
#pragma unroll
  for (int j = 0; j < 8; ++j) {
    s[j] = expf(s[j] - mx);
    sum += s[j];
  }
  __syncthreads();
  red[ig][col] = sum;
  __syncthreads();
  float tot = 0.f;
#pragma unroll
  for (int k = 0; k < 16; ++k) tot += red[k][col];
  float inv = 1.f / tot;
#pragma unroll
  for (int j = 0; j < 8; ++j) ab[(ig * 8 + j) * 128] = s[j] * inv;
}

// ---------------------------------------------------------------------------
// pvf_fused: out1+final fused per (b, h).  (unchanged from round 7)
// ---------------------------------------------------------------------------
__global__ __launch_bounds__(256, 2) void pvf_fused(
    const float* __restrict__ vseg, const float* __restrict__ att,
    const char* __restrict__ wu, const float* __restrict__ bup,
    float* __restrict__ oseg) {
  __shared__ char attnT[128 * 272];  // [w][136 f16] = attn^T
  __shared__ char vA[64 * 272];      // [c' chunk][136 f16]
  __shared__ char HT[128 * 144];     // [w][72 f16] = H'^T chunk
  const int t = threadIdx.x, lane = t & 63, w = t >> 6;
  const int l15 = lane & 15, g = lane >> 4;
  const int b = blockIdx.y, h = blockIdx.x;
  const float* ab = att + (long)b * 16384;
  const float* vb = vseg + (long)b * PB;
  float* Ob = oseg + (long)b * PB;

#pragma unroll
  for (int it = 0; it < 4; ++it) {
    const int f = t + 256 * it;       // 1024 = 32 i4 x 32 w4
    const int i4 = f >> 5, w4 = f & 31;
    const float4 r0 = *(const float4*)(ab + (4 * i4 + 0) * 128 + 4 * w4);
    const float4 r1 = *(const float4*)(ab + (4 * i4 + 1) * 128 + 4 * w4);
    const float4 r2 = *(const float4*)(ab + (4 * i4 + 2) * 128 + 4 * w4);
    const float4 r3 = *(const float4*)(ab + (4 * i4 + 3) * 128 + 4 * w4);
    *(uint2*)(attnT + (4 * w4 + 0) * 272 + swz(4 * w4 + 0, 8 * i4)) =
        make_uint2(pk2(r0.x, r1.x), pk2(r2.x, r3.x));
    *(uint2*)(attnT + (4 * w4 + 1) * 272 + swz(4 * w4 + 1, 8 * i4)) =
        make_uint2(pk2(r0.y, r1.y), pk2(r2.y, r3.y));
    *(uint2*)(attnT + (4 * w4 + 2) * 272 + swz(4 * w4 + 2, 8 * i4)) =
        make_uint2(pk2(r0.z, r1.z), pk2(r2.z, r3.z));
    *(uint2*)(attnT + (4 * w4 + 3) * 272 + swz(4 * w4 + 3, 8 * i4)) =
        make_uint2(pk2(r0.w, r1.w), pk2(r2.w, r3.w));
  }

  f32x4 acc2[4][8] = {};  // G2: o = w*64+16mf+4g+r, w' = 16nf+l15

  for (int cc = 0; cc < 4; ++cc) {
#pragma unroll
    for (int it = 0; it < 8; ++it) {
      const int f = t + 256 * it;     // 2048 = 64 rows x 32 float4
      const int cp = f >> 5, q4 = f & 31;
      const float4 v4 =
          *(const float4*)(vb + ((long)(cc * 64 + cp) * 128 + h) * 128 + 4 * q4);
      *(uint2*)(vA + cp * 272 + swz(cp, 8 * q4)) =
          make_uint2(pk2(v4.x, v4.y), pk2(v4.z, v4.w));
    }
    __syncthreads();

    f32x4 acc1[8] = {};
#pragma unroll
    for (int kf = 0; kf < 4; ++kf) {
      const f16x8 a = ldfrag((const f16*)vA, 272, w * 16 + l15, 64 * kf + 16 * g);
#pragma unroll
      for (int nf = 0; nf < 8; ++nf) {
        const f16x8 bf = ldfrag((const f16*)attnT, 272, 16 * nf + l15, 64 * kf + 16 * g);
        acc1[nf] = mfma16(a, bf, acc1[nf]);
      }
    }
#pragma unroll
    for (int nf = 0; nf < 8; ++nf)
#pragma unroll
      for (int r = 0; r < 4; ++r) {
        const int wp = 16 * nf + l15;
        const int cp = w * 16 + 4 * g + r;
        *(f16*)(HT + wp * 144 + swz(wp, 2 * cp)) = (f16)acc1[nf][r];
      }
    __syncthreads();

#pragma unroll
    for (int kf2 = 0; kf2 < 2; ++kf2) {
      const char* WU = wu + (long)(cc * 2 + kf2) * 16384;
      f16x8 af[4];
#pragma unroll
      for (int mf = 0; mf < 4; ++mf)
        af[mf] = ld64(WU, w * 64 + 16 * mf + l15, g);
#pragma unroll
      for (int nf = 0; nf < 8; ++nf) {
        const f16x8 bf = ldfrag((const f16*)HT, 144, 16 * nf + l15, 64 * kf2 + 16 * g);
#pragma unroll
        for (int mf = 0; mf < 4; ++mf)
          acc2[mf][nf] = mfma16(af[mf], bf, acc2[mf][nf]);
      }
    }
  }

#pragma unroll
  for (int mf = 0; mf < 4; ++mf)
#pragma unroll
    for (int nf = 0; nf < 8; ++nf)
#pragma unroll
      for (int r = 0; r < 4; ++r) {
        const int o = w * 64 + 16 * mf + 4 * g + r;
        const int wp = 16 * nf + l15;
        Ob[(long)o * HW + h * 128 + wp] = acc2[mf][nf][r] + bup[o];
      }
}

// ---------------------------------------------------------------------------
// Fallback kernels (used only if ws_size < WS_NEED).
// ---------------------------------------------------------------------------
__global__ __launch_bounds__(128) void softmax_kernel(
    const float* __restrict__ part, float* __restrict__ att,
    float* __restrict__ gout, const float* __restrict__ gin) {
  const int b = blockIdx.x, t = threadIdx.x;
  if (b == 0 && t == 0) gout[0] = gin[0];
  const float* pp = part + (long)b * 32 * 16384;
  float* ab = att + (long)b * 16384;
  float mx = -3.0e38f;
  for (int i = 0; i < 128; ++i) {
    float s = 0.f;
#pragma unroll
    for (int c = 0; c < 32; ++c) s += pp[(long)c * 16384 + i * 128 + t];
    ab[i * 128 + t] = s;
    mx = fmaxf(mx, s);
  }
  float sum = 0.f;
  for (int i = 0; i < 128; ++i) {
    float e = expf(ab[i * 128 + t] - mx);
    sum += e;
    ab[i * 128 + t] = e;
  }
  float inv = 1.f / sum;
  for (int i = 0; i < 128; ++i) ab[i * 128 + t] *= inv;
}

template <int MODE>
__global__ __launch_bounds__(256) void proj_kernel(
    const float* __restrict__ x, const float* __restrict__ Wm,
    float* __restrict__ out) {
  constexpr int SB = 80;
  __shared__ f16 Wh[256 * 40];
  __shared__ f16 Wl[256 * 40];
  __shared__ f16 Xh[64 * 40];
  __shared__ f16 Xl[64 * 40];

  const int t = threadIdx.x;
  const int lane = t & 63;
  const int w = t >> 6;
  const int l15 = lane & 15;
  const int g = lane >> 4;
  const int b = blockIdx.y;
  const int hw0 = blockIdx.x * 64;
  const float* xb = x + (long)b * PB;

  f32x4 acc[4][4] = {};

  for (int kc = 0; kc < 256; kc += 32) {
#pragma unroll
    for (int it = 0; it < 8; ++it) {
      int f4 = t + 256 * it;
      int o = f4 >> 3, c4 = f4 & 7;
      float4 v = *(const float4*)(Wm + o * 256 + kc + 4 * c4);
      unsigned h01, l01, h23, l23;
      split_pk2(v.x, v.y, h01, l01);
      split_pk2(v.z, v.w, h23, l23);
      int kb = swz(o, 8 * c4);
      *(uint2*)((char*)Wh + o * SB + kb) = make_uint2(h01, h23);
      *(uint2*)((char*)Wl + o * SB + kb) = make_uint2(l01, l23);
    }
    {
      int c = t & 63, rq = t >> 6;
      float vs[8];
#pragma unroll
      for (int r = 0; r < 8; ++r)
        vs[r] = xb[(long)(kc + 8 * rq + r) * HW + hw0 + c];
#pragma unroll
      for (int u = 0; u < 2; ++u) {
        unsigned h0, l0, h1, l1;
        split_pk2(vs[4 * u], vs[4 * u + 1], h0, l0);
        split_pk2(vs[4 * u + 2], vs[4 * u + 3], h1, l1);
        int kb = swz(c, 16 * rq + 8 * u);
        *(uint2*)((char*)Xh + c * SB + kb) = make_uint2(h0, h1);
        *(uint2*)((char*)Xl + c * SB + kb) = make_uint2(l0, l1);
      }
    }
    __syncthreads();

    f16x8 wfh[4], wfl[4], xfh[4], xfl[4];
#pragma unroll
    for (int f = 0; f < 4; ++f) {
      int wr = 64 * w + 16 * f + l15;
      int xr = 16 * f + l15;
      wfh[f] = ldfrag(Wh, SB, wr, 16 * g);
      wfl[f] = ldfrag(Wl, SB, wr, 16 * g);
      xfh[f] = ldfrag(Xh, SB, xr, 16 * g);
      xfl[f] = ldfrag(Xl, SB, xr, 16 * g);
    }
#pragma unroll
    for (int mf = 0; mf < 4; ++mf)
#pragma unroll
      for (int nf = 0; nf < 4; ++nf) {
        if constexpr (MODE == 0) {
          acc[mf][nf] = mfma16(wfh[mf], xfh[nf], acc[mf][nf]);
          acc[mf][nf] = mfma16(wfh[mf], xfl[nf], acc[mf][nf]);
          acc[mf][nf] = mfma16(wfl[mf], xfh[nf], acc[mf][nf]);
        } else {
          acc[mf][nf] = mfma16(xfh[mf], wfh[nf], acc[mf][nf]);
          acc[mf][nf] = mfma16(xfh[mf], wfl[nf], acc[mf][nf]);
          acc[mf][nf] = mfma16(xfl[mf], wfh[nf], acc[mf][nf]);
        }
      }
    __syncthreads();
  }

  float* ob = out + (long)b * PB;
#pragma unroll
  for (int mf = 0; mf < 4; ++mf)
#pragma unroll
    for (int nf = 0; nf < 4; ++nf)
#pragma unroll
      for (int r = 0; r < 4; ++r) {
        float v = acc[mf][nf][r];
        v = v > 0.f ? v : 0.f;
        if constexpr (MODE == 0) {
          int o = 64 * w + 16 * mf + 4 * g + r;
          int hw = hw0 + 16 * nf + l15;
          ob[(long)o * HW + hw] = v;
        } else {
          int hw = hw0 + 16 * mf + 4 * g + r;
          int o = 64 * w + 16 * nf + l15;
          ob[((o & 1) ? HALF : 0) + (long)hw * 128 + (o >> 1)] = v;
        }
      }
}

__global__ __launch_bounds__(256) void out1_fb(
    const float* __restrict__ vseg, const float* __restrict__ att,
    float* __restrict__ outseg) {
  constexpr int SB = 272;
  __shared__ f16 Va[64 * 136], Ba[128 * 136];
  const int t = threadIdx.x, lane = t & 63, w = t >> 6;
  const int l15 = lane & 15, g = lane >> 4;
  const int b = blockIdx.y;
  const long j0 = (long)blockIdx.x * 64;
  const float* vb = vseg + (long)b * PB + j0 * 128;
  const float* ab = att + (long)b * 16384;

#pragma unroll
  for (int it = 0; it < 8; ++it) {
    int f4 = t + 256 * it;
    int j = f4 >> 5, c4 = f4 & 31;
    float4 v = *(const float4*)(vb + (long)j * 128 + 4 * c4);
    int kb = swz(j, 8 * c4);
    *(uint2*)((char*)Va + j * SB + kb) = make_uint2(pk2(v.x, v.y), pk2(v.z, v.w));
  }
  {
    int c = t & 127, rh = t >> 7;
#pragma unroll
    for (int uu = 0; uu < 16; ++uu) {
      int i0 = 64 * rh + 4 * uu;
      float v0 = ab[(i0 + 0) * 128 + c];
      float v1 = ab[(i0 + 1) * 128 + c];
      float v2 = ab[(i0 + 2) * 128 + c];
      float v3 = ab[(i0 + 3) * 128 + c];
      int kb = swz(c, 2 * i0);
      *(uint2*)((char*)Ba + c * SB + kb) = make_uint2(pk2(v0, v1), pk2(v2, v3));
    }
  }
  __syncthreads();

  f32x4 acc[2][4] = {};
#pragma unroll
  for (int kf = 0; kf < 4; ++kf) {
    f16x8 af[2], bf[4];
#pragma unroll
    for (int mf = 0; mf < 2; ++mf)
      af[mf] = ldfrag(Va, SB, (w & 1) * 32 + 16 * mf + l15, 64 * kf + 16 * g);
#pragma unroll
    for (int nf = 0; nf < 4; ++nf)
      bf[nf] = ldfrag(Ba, SB, (w >> 1) * 64 + 16 * nf + l15, 64 * kf + 16 * g);
#pragma unroll
    for (int mf = 0; mf < 2; ++mf)
#pragma unroll
      for (int nf = 0; nf < 4; ++nf)
        acc[mf][nf] = mfma16(af[mf], bf[nf], acc[mf][nf]);
  }

  float* ob = outseg + (long)b * PB;
#pragma unroll
  for (int mf = 0; mf < 2; ++mf)
#pragma unroll
    for (int nf = 0; nf < 4; ++nf)
#pragma unroll
      for (int r = 0; r < 4; ++r) {
        long j = j0 + (w & 1) * 32 + 16 * mf + 4 * g + r;
        int i2 = (w >> 1) * 64 + 16 * nf + l15;
        ob[j * 128 + i2] = acc[mf][nf][r];
      }
}

__global__ __launch_bounds__(256) void final_kernel(
    float* __restrict__ outseg, const float* __restrict__ Wup,
    const float* __restrict__ bup, const float* __restrict__ gin) {
  constexpr int SB = 144;
  __shared__ f16 Ah[256 * 72], Bh[64 * 72];
  const int t = threadIdx.x, lane = t & 63, w = t >> 6;
  const int l15 = lane & 15, g = lane >> 4;
  const int b = blockIdx.y;
  const int hw0 = blockIdx.x * 64;
  const float gamma = gin[0];
  float* Hb = outseg + (long)b * PB;

  f32x4 acc[4][4] = {};

  for (int kc = 0; kc < 256; kc += 64) {
#pragma unroll
    for (int it = 0; it < 16; ++it) {
      int f4 = t + 256 * it;
      int o = f4 >> 4, c4 = f4 & 15;
      float4 v = *(const float4*)(Wup + o * 256 + kc + 4 * c4);
      int kb = swz(o, 8 * c4);
      *(uint2*)((char*)Ah + o * SB + kb) =
          make_uint2(pk2(v.x * gamma, v.y * gamma), pk2(v.z * gamma, v.w * gamma));
    }
    {
      int n = t & 63, rq = t >> 6;
#pragma unroll
      for (int uu = 0; uu < 4; ++uu) {
        int r0 = 16 * rq + 4 * uu;
        float v0 = Hb[(long)(kc + r0 + 0) * HW + hw0 + n];
        float v1 = Hb[(long)(kc + r0 + 1) * HW + hw0 + n];
        float v2 = Hb[(long)(kc + r0 + 2) * HW + hw0 + n];
        float v3 = Hb[(long)(kc + r0 + 3) * HW + hw0 + n];
        int kb = swz(n, 2 * r0);
        *(uint2*)((char*)Bh + n * SB + kb) = make_uint2(pk2(v0, v1), pk2(v2, v3));
      }
    }
    __syncthreads();

    f16x8 af[4][2], bf[4][2];
#pragma unroll
    for (int f = 0; f < 4; ++f)
#pragma unroll
      for (int kf = 0; kf < 2; ++kf) {
        af[f][kf] = ldfrag(Ah, SB, 64 * w + 16 * f + l15, 64 * kf + 16 * g);
        bf[f][kf] = ldfrag(Bh, SB, 16 * f + l15, 64 * kf + 16 * g);
      }
#pragma unroll
    for (int mf = 0; mf < 4; ++mf)
#pragma unroll
      for (int nf = 0; nf < 4; ++nf) {
        acc[mf][nf] = mfma16(af[mf][0], bf[nf][0], acc[mf][nf]);
        acc[mf][nf] = mfma16(af[mf][1], bf[nf][1], acc[mf][nf]);
      }
    __syncthreads();
  }

#pragma unroll
  for (int mf = 0; mf < 4; ++mf)
#pragma unroll
    for (int nf = 0; nf < 4; ++nf)
#pragma unroll
      for (int r = 0; r < 4; ++r) {
        int o = 64 * w + 16 * mf + 4 * g + r;
        int hw = hw0 + 16 * nf + l15;
        Hb[(long)o * HW + hw] = acc[mf][nf][r] + bup[o];
      }
}

// ---------------------------------------------------------------------------
extern "C" void kernel_launch(void* const* d_in, const int* in_sizes, int n_in,
                              void* d_out, int out_size, void* d_ws, size_t ws_size,
                              hipStream_t stream) {
  (void)in_sizes; (void)n_in; (void)out_size;

  const float* x  = (const float*)d_in[0];
  const float* Wq = (const float*)d_in[1];
  const float* Wk = (const float*)d_in[2];
  const float* Wv = (const float*)d_in[3];
  const float* gm = (const float*)d_in[4];
  const float* Wu = (const float*)d_in[5];
  const float* bu = (const float*)d_in[6];

  float* out  = (float*)d_out;
  float* oseg = out;                 // [B,256,128,128] final (scratch first)
  float* qseg = out + 67108864L;     // [B,128,32768]
  float* kseg = out + 134217728L;    // [B,32768,128]
  float* vseg = out + 201326592L;    // [B,32768,128]
  float* gseg = out + 268435456L;    // [1]
  float* aseg = out + 268435457L;    // [B,128,128]

  dim3 blk(256);
  if (ws_size >= (size_t)WS_NEED && d_ws != nullptr) {
    char* ws = (char*)d_ws;
    prep_w<<<dim3(8, 4), blk, 0, stream>>>(Wq, Wk, Wv, Wu, gm, ws);
    qkv_fused4<<<dim3(256, 16), dim3(512), 0, stream>>>(
        x, ws + WH_OFF, ws + WL_OFF, ws + WH_OFF + 131072, ws + WL_OFF + 131072,
        ws + WH_OFF + 262144, qseg, kseg, vseg);
    spart_kernel<<<dim3(32, 16), blk, 0, stream>>>(qseg, kseg, oseg);
    reduce_s<<<dim3(128, 16), dim3(128), 0, stream>>>(oseg, aseg, gseg, gm);
    softmax2<<<dim3(8, 16), blk, 0, stream>>>(aseg);
    pvf_fused<<<dim3(128, 16), blk, 0, stream>>>(vseg, aseg, ws + WU_OFF, bu, oseg);
  } else {
    proj_kernel<0><<<dim3(256, 16), blk, 0, stream>>>(x, Wq, qseg);
    proj_kernel<1><<<dim3(256, 16), blk, 0, stream>>>(x, Wk, kseg);
    proj_kernel<1><<<dim3(256, 16), blk, 0, stream>>>(x, Wv, vseg);
    spart_kernel<<<dim3(32, 16), blk, 0, stream>>>(qseg, kseg, oseg);
    softmax_kernel<<<dim3(16), dim3(128), 0, stream>>>(oseg, aseg, gseg, gm);
    out1_fb<<<dim3(512, 16), blk, 0, stream>>>(vseg, aseg, oseg);
    final_kernel<<<dim3(256, 16), blk, 0, stream>>>(oseg, Wu, bu, gm);
  }
}